// Round 4
// baseline (15879.137 us; speedup 1.0000x reference)
//
#include <hip/hip_runtime.h>
#include <hip/hip_fp8.h>
#include <math.h>

// SimpleNeuroSAT on MI355X — round 19: fuse CL gather into l_update.
//  (1) k_cl_gather eliminated: its CSR gather (per-literal clause sum from
//      fp8 Cb8) now feeds k_l_update's LDS staging region [80:160) directly.
//      Removes the CLb 32MB buffer and its 64MB/round HBM round-trip plus one
//      launch from the serial per-round chain.
//  (2) k_l_update gets the bijective XCD swizzle: literal ranges are
//      contiguous per XCD, and (via round-18's clause sort) each literal's
//      first-position clause run is contiguous in Cb8 -> L2-local gathers.
// Keeps: clause first-lit sort, 128B-padded fp8 rows, nt Cb stream, inline
// L norm, packed loss cells, converged staging, int4 lofs.
// Finding so far: rounds 16-18 all within +-1% noise (15.54-15.79ms) -> the
// floor is the serial chain + gather latency, not BW/footprint/locality.

#define NROUNDS 32
#define NORM_EPS 1e-3f
#define LOSS_EPS 1e-8f

static constexpr int NV_CONST = 100000;
static constexpr int NG_CONST = 100;

typedef __attribute__((ext_vector_type(8))) short short8;
typedef __attribute__((ext_vector_type(8))) unsigned char uchar8;
typedef __attribute__((ext_vector_type(16))) unsigned char uchar16;
typedef __attribute__((ext_vector_type(4))) float f32x4;

__device__ __forceinline__ short f2bf(float f) {
    union { float f; unsigned u; } x; x.f = f;
    unsigned r = x.u + 0x7fffu + ((x.u >> 16) & 1u);   // RNE
    return (short)(r >> 16);
}
__device__ __forceinline__ float bf2f(short s) {
    union { unsigned u; float f; } x; x.u = ((unsigned)(unsigned short)s) << 16;
    return x.f;
}
__device__ __forceinline__ unsigned char f2q8(float f) {
    f = fminf(fmaxf(f, -448.f), 448.f);    // e4m3fn finite range
    __hip_fp8_e4m3 t(f);
    return t.__x;
}
__device__ __forceinline__ float q82f(unsigned char b) {
    __hip_fp8_e4m3 t; t.__x = b;
    return (float)t;
}

// bijective XCD-aware block swizzle (m204): contiguous chunk per XCD
__device__ __forceinline__ int xcd_swz(int b, int nb) {
    int q = nb >> 3, r = nb & 7;
    int xcd = b & 7, idx = b >> 3;
    return (xcd < r ? xcd * (q + 1) : r * (q + 1) + (xcd - r) * q) + idx;
}

// ---------------- setup kernels ----------------

__global__ void k_zero_i(int* __restrict__ p, int n) {
    int i = blockIdx.x * 256 + threadIdx.x;
    if (i < n) p[i] = 0;
}
__global__ void k_fill_b(short* __restrict__ p, int n, const float* __restrict__ vp) {
    int i = blockIdx.x * 256 + threadIdx.x;
    if (i < n) p[i] = f2bf(*vp);
}
__global__ void k_fill_q8(unsigned char* __restrict__ p, int n, const float* __restrict__ vp) {
    int i = blockIdx.x * 256 + threadIdx.x;
    if (i < n) p[i] = f2q8(*vp);
}
__global__ void k_copy_int(int* __restrict__ dst, const int* __restrict__ src, int n) {
    int i = blockIdx.x * 256 + threadIdx.x;
    if (i < n) dst[i] = src[i];
}
// zero all slabs; slab[0] = identity for BOTH C and L (mean 0, rstd exactly 1)
__global__ void k_init_slabs(float* __restrict__ slabC, float* __restrict__ slabL,
                             float* __restrict__ loss_a, float nclf, float nlf) {
    int i = blockIdx.x * 256 + threadIdx.x;
    if (i < 33 * 160) {
        slabC[i] = (i >= 80 && i < 160) ? nclf * (1.f - NORM_EPS) : 0.f;
        slabL[i] = (i >= 80 && i < 160) ? nlf * (1.f - NORM_EPS) : 0.f;
    }
    if (i == 0) loss_a[0] = 0.f;
}

// litrow + packed loss cells + literal-CSR counts + first-lit histogram
__global__ void k_litrow(const int* __restrict__ lit_var, const int* __restrict__ lit_neg,
                         int* __restrict__ litrow, int* __restrict__ cellpk,
                         int* __restrict__ counts, int* __restrict__ fhist,
                         int ncell, int nv) {
    int i = blockIdx.x * 256 + threadIdx.x;
    if (i < ncell) {
        int vv = lit_var[i], ng = lit_neg[i];
        int r = vv + ng * nv;
        litrow[i] = r;
        cellpk[i] = vv | (ng << 31);
        atomicAdd(&counts[r], 1);
        if (i % 3 == 0) atomicAdd(&fhist[r], 1);   // clause key = first cell's row
    }
}

__launch_bounds__(1024)
__global__ void k_scan4(const int* __restrict__ counts, int* __restrict__ row_ptr,
                        int n, int total) {
    __shared__ int sd[1024];
    __shared__ int carry;
    int tid = threadIdx.x;
    if (tid == 0) carry = 0;
    __syncthreads();
    for (int base = 0; base < n; base += 4096) {
        int i0 = base + tid * 4;
        int a0 = (i0 + 0 < n) ? counts[i0 + 0] : 0;
        int a1 = (i0 + 1 < n) ? counts[i0 + 1] : 0;
        int a2 = (i0 + 2 < n) ? counts[i0 + 2] : 0;
        int a3 = (i0 + 3 < n) ? counts[i0 + 3] : 0;
        int s = a0 + a1 + a2 + a3;
        sd[tid] = s;
        __syncthreads();
        for (int off = 1; off < 1024; off <<= 1) {
            int t = (tid >= off) ? sd[tid - off] : 0;
            __syncthreads();
            sd[tid] += t;
            __syncthreads();
        }
        int excl = carry + sd[tid] - s;
        if (i0 + 0 < n) row_ptr[i0 + 0] = excl;
        if (i0 + 1 < n) row_ptr[i0 + 1] = excl + a0;
        if (i0 + 2 < n) row_ptr[i0 + 2] = excl + a0 + a1;
        if (i0 + 3 < n) row_ptr[i0 + 3] = excl + a0 + a1 + a2;
        __syncthreads();
        if (tid == 0) carry += sd[1023];
        __syncthreads();
    }
    if (tid == 0) row_ptr[n] = total;
}

// place clauses into first-lit-sorted order; write permuted lofs4 + newpos
__global__ void k_place(const int* __restrict__ litrow, int* __restrict__ fcur,
                        int* __restrict__ newpos, int* __restrict__ lofs4, int ncl) {
    int c = blockIdx.x * 256 + threadIdx.x;
    if (c < ncl) {
        int k = litrow[3 * c];
        int np = atomicAdd(&fcur[k], 1);
        newpos[c] = np;
        lofs4[np * 4 + 0] = litrow[3 * c + 0] * 8;
        lofs4[np * 4 + 1] = litrow[3 * c + 1] * 8;
        lofs4[np * 4 + 2] = litrow[3 * c + 2] * 8;
    }
}

__global__ void k_fill_csr(const int* __restrict__ litrow, const int* __restrict__ clause_idx,
                           const int* __restrict__ newpos,
                           int* __restrict__ cursor, int* __restrict__ cl_of, int ncell) {
    int i = blockIdx.x * 256 + threadIdx.x;
    if (i < ncell) {
        int r = litrow[i];
        int pos = atomicAdd(&cursor[r], 1);
        cl_of[pos] = newpos[clause_idx[i]];
    }
}

// Wp frag t=(nb*KB+kb)*64+lane holds W[kb*32+quad*8+j][nb*16+(lane&15)], zero-padded.
__global__ void k_pack_w(const float* __restrict__ W, short* __restrict__ Wp,
                         int K, int N, int KB, int NB) {
    int t = blockIdx.x * 256 + threadIdx.x;
    int tot = NB * KB * 64;
    if (t >= tot) return;
    int lane = t & 63;
    int kb = (t >> 6) % KB;
    int nb = t / (64 * KB);
    int quad = lane >> 4, l15 = lane & 15;
    int n = nb * 16 + l15;
#pragma unroll
    for (int j = 0; j < 8; ++j) {
        int k = kb * 32 + quad * 8 + j;
        float f = (k < K && n < N) ? W[(size_t)k * N + n] : 0.f;
        Wp[(size_t)t * 8 + j] = f2bf(f);
    }
}

// ---------------- MFMA building blocks ----------------

template <int KB, int NB>
__device__ __forceinline__ void mfma_layer(const short* lds, int SK,
                                           const short8* __restrict__ Wp,
                                           f32x4* acc, int lane, int arow) {
    const int quad8 = (lane >> 4) * 8;
    short8 a[KB];
#pragma unroll
    for (int kb = 0; kb < KB; ++kb)
        a[kb] = *(const short8*)(lds + arow * SK + kb * 32 + quad8);
#pragma unroll
    for (int kb = 0; kb < KB; ++kb)
#pragma unroll
        for (int nb = 0; nb < NB; ++nb)
            acc[nb] = __builtin_amdgcn_mfma_f32_16x16x32_bf16(
                a[kb], Wp[(nb * KB + kb) * 64 + lane], acc[nb], 0, 0, 0);
}

// wave-private: writes only rows wr0..wr0+15 (same stripe the wave reads)
template <int NB>
__device__ __forceinline__ void write_hidden(short* ldsH, int SKH, const f32x4* acc,
                                             const float* __restrict__ bias,
                                             int l15, int quad, int wr0) {
#pragma unroll
    for (int nb = 0; nb < NB; ++nb) {
        int c = nb * 16 + l15;
        float bv = bias[c];
#pragma unroll
        for (int reg = 0; reg < 4; ++reg) {
            int row = wr0 + quad * 4 + reg;
            float v = acc[nb][reg] + bv;
            v = fminf(fmaxf(v, 0.f), 6.f);
            ldsH[row * SKH + c] = f2bf(v);
        }
    }
}

// compute mean/rstd from an accum slab into shared sS[160] (callers sync after)
__device__ __forceinline__ void load_stats(const float* __restrict__ slab, float Minv,
                                           float* sS, int tid) {
    if (tid < 80) {
        float m = slab[tid] * Minv;
        float v = slab[80 + tid] * Minv - m * m;
        sS[tid] = m;
        sS[80 + tid] = rsqrtf(v + NORM_EPS);
    }
}

// ---------------- fused C update (16B fp8 LC gather, 128B-aligned rows) ----------------
__launch_bounds__(256, 2)
__global__ void k_c_update(short* __restrict__ Cb, unsigned char* __restrict__ Cb8,
                           const unsigned char* __restrict__ Lb8,
                           const int4* __restrict__ lofs4, const float* __restrict__ scp,
                           const short8* __restrict__ W0p, const float* __restrict__ b0,
                           const short8* __restrict__ W1p, const float* __restrict__ b1,
                           const float* __restrict__ prevSlab, float* __restrict__ nextSlab,
                           float Minv, int ncl) {
    constexpr int SK = 168;
    __shared__ short lds[64 * SK];
    __shared__ float sred[160], sC[160];
    const int lane = threadIdx.x, wy = threadIdx.y, tid = wy * 64 + lane;
    const int r0 = xcd_swz(blockIdx.x, gridDim.x) * 64;
    const int rows = (ncl - r0 < 64) ? (ncl - r0) : 64;

    if (tid < 160) sred[tid] = 0.f;
    load_stats(prevSlab, Minv, sC, tid);
    __syncthreads();

    const float s = *scp;
    const short8* Cbv = (const short8*)Cb;
    const uchar16* Lq = (const uchar16*)Lb8;

    // Converged direct staging: 64 rows x 10 bf16 chunks (640 items).
    // Cb is a full-round-reuse-distance stream: non-temporal.
#pragma unroll
    for (int u = 0; u < 3; ++u) {
        int it = tid + u * 256;
        int itc = (it < 640) ? it : 639;
        int lr = itc / 10, c = itc - lr * 10;
        int cl = r0 + ((lr < rows) ? lr : rows - 1);
        short8 v = __builtin_nontemporal_load(&Cbv[(size_t)cl * 10 + c]);
        int col = c * 8;
        short8 o;
#pragma unroll
        for (int j = 0; j < 8; ++j)
            o[j] = f2bf((bf2f(v[j]) - sC[col + j]) * sC[80 + col + j]);
        if (it < 640)
            *(short8*)(lds + lr * SK + col) = o;
    }
    // Converged gather staging: 64 rows x 5 fp8 16B chunks (320 items).
    // First-lit (o4.x) is sorted across the block -> near-sequential, L2-local.
#pragma unroll
    for (int u = 0; u < 2; ++u) {
        int it = tid + u * 256;
        int itc = (it < 320) ? it : 319;
        int lr = itc / 5, cc = itc - lr * 5;
        int cl = r0 + ((lr < rows) ? lr : rows - 1);
        int4 o4 = lofs4[cl];
        uchar16 va = Lq[(size_t)o4.x + cc];
        uchar16 vb = Lq[(size_t)o4.y + cc];
        uchar16 vc = Lq[(size_t)o4.z + cc];
        short8 o0, o1;
#pragma unroll
        for (int j = 0; j < 8; ++j) {
            o0[j] = f2bf((q82f(va[j]) + q82f(vb[j]) + q82f(vc[j])) * s);
            o1[j] = f2bf((q82f(va[8 + j]) + q82f(vb[8 + j]) + q82f(vc[8 + j])) * s);
        }
        if (it < 320) {
            *(short8*)(lds + lr * SK + 80 + cc * 16) = o0;
            *(short8*)(lds + lr * SK + 80 + cc * 16 + 8) = o1;
        }
    }
    __syncthreads();   // staging crosses stripes; everything after is wave-private

    const int quad = lane >> 4, l15 = lane & 15, wr0 = wy * 16, arow = wr0 + l15;

    f32x4 acc[10];
#pragma unroll
    for (int nb = 0; nb < 10; ++nb) { f32x4 z = {0.f, 0.f, 0.f, 0.f}; acc[nb] = z; }
    mfma_layer<5, 10>(lds, SK, W0p, acc, lane, arow);
    write_hidden<10>(lds, SK, acc, b0, l15, quad, wr0);

    f32x4 acc2[5];
#pragma unroll
    for (int nb = 0; nb < 5; ++nb) { f32x4 z = {0.f, 0.f, 0.f, 0.f}; acc2[nb] = z; }
    mfma_layer<5, 5>(lds, SK, W1p, acc2, lane, arow);

#pragma unroll
    for (int nb = 0; nb < 5; ++nb) {
        int cc = nb * 16 + l15;
        float bv = b1[cc];
        float s1 = 0.f, s2 = 0.f;
#pragma unroll
        for (int reg = 0; reg < 4; ++reg) {
            int lr = wr0 + quad * 4 + reg;
            if (lr < rows) {
                float v = acc2[nb][reg] + bv;
                __builtin_nontemporal_store(f2bf(v), &Cb[(size_t)(r0 + lr) * 80 + cc]);
                Cb8[(size_t)(r0 + lr) * 128 + cc] = f2q8(v);
                s1 += v; s2 += v * v;
            }
        }
        s1 += __shfl_xor(s1, 16); s1 += __shfl_xor(s1, 32);
        s2 += __shfl_xor(s2, 16); s2 += __shfl_xor(s2, 32);
        if (quad == 0) { atomicAdd(&sred[cc], s1); atomicAdd(&sred[80 + cc], s2); }
    }
    __syncthreads();
    if (tid < 160) atomicAdd(&nextSlab[tid], sred[tid]);
}

// ---------------- fused L update (CSR CL gather + MLP, inline L norm) ----------------
// paired rows [vb,vb+32) u [vb+nv,vb+nv+32); own+flip rows are block-local, so
// reading old Lraw and overwriting it in the epilogue is hazard-free.
// CL messages gathered here directly from fp8 Cb8 via literal CSR (no CLb).
__launch_bounds__(256, 2)
__global__ void k_l_update(short* __restrict__ Lraw,
                           const unsigned char* __restrict__ Cb8,
                           const int* __restrict__ row_ptr, const int* __restrict__ cl_of,
                           const float* __restrict__ clscp,
                           const float* __restrict__ cSlab, float MinvC,
                           const short8* __restrict__ W0p, const float* __restrict__ b0,
                           const short8* __restrict__ W1p, const float* __restrict__ b1,
                           const float* __restrict__ prevSlab, float* __restrict__ nextSlab,
                           float MinvL, int nv) {
    constexpr int SK = 264;
    __shared__ short lds[64 * SK];             // input K=256, then hidden 240+16pad
    __shared__ float sred[160], sL[160], sC[160];
    const int lane = threadIdx.x, wy = threadIdx.y, tid = wy * 64 + lane;
    const int vb = xcd_swz(blockIdx.x, gridDim.x) * 32;

    if (tid < 160) sred[tid] = 0.f;
    load_stats(prevSlab, MinvL, sL, tid);
    load_stats(cSlab, MinvC, sC, tid);
    __syncthreads();

    const short8* Lr8 = (const short8*)Lraw;
    // Phase 1: issue direct L loads (own + flip + zero tail), 64 rows x 22 chunks.
    short8 vals[6];
#pragma unroll
    for (int u = 0; u < 6; ++u) {
        int it = tid + u * 256;
        int itc = (it < 1408) ? it : 1407;
        int lr = itc / 22, c = itc - lr * 22;
        int own = (lr < 32) ? vb + lr : vb + nv + (lr - 32);
        int opp = (lr < 32) ? vb + nv + lr : vb + (lr - 32);
        int row = (c < 10) ? own : opp;               // c>=20 reads own c0 (discarded)
        int cc = (c < 10) ? c : ((c < 20) ? c - 10 : 0);
        vals[u] = Lr8[(size_t)row * 10 + cc];
    }

    // Phase 2: CSR CL gather, 64 rows x 5 fp8 16B chunks (320 items).
    // Row's clause list (via round-18 sort) has a contiguous first-lit run.
    const float cs = *clscp;
    const uchar16* Cq = (const uchar16*)Cb8;
#pragma unroll
    for (int u = 0; u < 2; ++u) {
        int it = tid + u * 256;
        if (it < 320) {
            int lr = it / 5, c16 = it - lr * 5;
            int r = (lr < 32) ? vb + lr : vb + nv + (lr - 32);
            int p0 = row_ptr[r], p1 = row_ptr[r + 1];
            float a[16];
#pragma unroll
            for (int j = 0; j < 16; ++j) a[j] = 0.f;
            int p = p0;
            for (; p + 4 <= p1; p += 4) {
                int i0 = cl_of[p], i1 = cl_of[p + 1], i2 = cl_of[p + 2], i3 = cl_of[p + 3];
                uchar16 v0 = Cq[(size_t)i0 * 8 + c16];
                uchar16 v1 = Cq[(size_t)i1 * 8 + c16];
                uchar16 v2 = Cq[(size_t)i2 * 8 + c16];
                uchar16 v3 = Cq[(size_t)i3 * 8 + c16];
#pragma unroll
                for (int j = 0; j < 16; ++j)
                    a[j] += (q82f(v0[j]) + q82f(v1[j])) + (q82f(v2[j]) + q82f(v3[j]));
            }
            for (; p < p1; ++p) {
                uchar16 v = Cq[(size_t)cl_of[p] * 8 + c16];
#pragma unroll
                for (int j = 0; j < 16; ++j) a[j] += q82f(v[j]);
            }
            float n = (float)(p1 - p0);
            int col = c16 * 16;
            short8 o0, o1;
#pragma unroll
            for (int j = 0; j < 8; ++j) {
                o0[j] = f2bf((a[j] - n * sC[col + j]) * sC[80 + col + j] * cs);
                o1[j] = f2bf((a[8 + j] - n * sC[col + 8 + j]) * sC[80 + col + 8 + j] * cs);
            }
            *(short8*)(lds + lr * SK + 80 + c16 * 16) = o0;
            *(short8*)(lds + lr * SK + 80 + c16 * 16 + 8) = o1;
        }
    }

    // Phase 3: normalize + store the direct L chunks.
#pragma unroll
    for (int u = 0; u < 6; ++u) {
        int it = tid + u * 256;
        int itc = (it < 1408) ? it : 1407;
        int lr = itc / 22, c = itc - lr * 22;
        short8 w = vals[u];
        if (c < 20) {
            int base = ((c < 10) ? c : c - 10) * 8;
#pragma unroll
            for (int j = 0; j < 8; ++j)
                w[j] = f2bf((bf2f(w[j]) - sL[base + j]) * sL[80 + base + j]);
        } else {
            short8 z = {0, 0, 0, 0, 0, 0, 0, 0};
            w = z;
        }
        int o = (c < 10) ? c * 8 : (c < 20) ? 160 + (c - 10) * 8 : 240 + (c - 20) * 8;
        if (it < 1408)
            *(short8*)(lds + lr * SK + o) = w;
    }
    __syncthreads();   // staging crosses stripes; rest is wave-private

    const int quad = lane >> 4, l15 = lane & 15, wr0 = wy * 16, arow = wr0 + l15;

    f32x4 acc[15];
#pragma unroll
    for (int nb = 0; nb < 15; ++nb) { f32x4 z = {0.f, 0.f, 0.f, 0.f}; acc[nb] = z; }
    mfma_layer<8, 15>(lds, SK, W0p, acc, lane, arow);
    write_hidden<15>(lds, SK, acc, b0, l15, quad, wr0);
    {   // zero-pad hidden cols 240..255 of OWN stripe (wave-private)
        int row = wr0 + (lane >> 2);
        int c = 240 + (lane & 3) * 4;
        short4 z; z.x = 0; z.y = 0; z.z = 0; z.w = 0;
        *(short4*)(lds + row * SK + c) = z;
    }

    f32x4 acc2[5];
#pragma unroll
    for (int nb = 0; nb < 5; ++nb) { f32x4 z = {0.f, 0.f, 0.f, 0.f}; acc2[nb] = z; }
    mfma_layer<8, 5>(lds, SK, W1p, acc2, lane, arow);

#pragma unroll
    for (int nb = 0; nb < 5; ++nb) {
        int cc = nb * 16 + l15;
        float bv = b1[cc];
        float s1 = 0.f, s2 = 0.f;
#pragma unroll
        for (int reg = 0; reg < 4; ++reg) {
            int lr = wr0 + quad * 4 + reg;
            int rabs = (lr < 32) ? vb + lr : vb + nv + (lr - 32);
            float v = acc2[nb][reg] + bv;
            Lraw[(size_t)rabs * 80 + cc] = f2bf(v);
            s1 += v; s2 += v * v;
        }
        s1 += __shfl_xor(s1, 16); s1 += __shfl_xor(s1, 32);
        s2 += __shfl_xor(s2, 16); s2 += __shfl_xor(s2, 32);
        if (quad == 0) { atomicAdd(&sred[cc], s1); atomicAdd(&sred[80 + cc], s2); }
    }
    __syncthreads();
    if (tid < 160) atomicAdd(&nextSlab[tid], sred[tid]);
}

// ---------------- fused V head (4 layers; emits Lb8 fp8 for next round) ----------------
__launch_bounds__(256, 2)
__global__ void k_v_head(const short* __restrict__ Lraw, const float* __restrict__ slab,
                         float Minv,
                         const short8* __restrict__ W0p, const float* __restrict__ b0,
                         const short8* __restrict__ W1p, const float* __restrict__ b1,
                         const short8* __restrict__ W2p, const float* __restrict__ b2,
                         const float* __restrict__ W3, const float* __restrict__ b3,
                         float* __restrict__ logits,
                         unsigned char* __restrict__ Lb8, int nv) {
    constexpr int SK = 168;
    __shared__ short lds[64 * SK];
    __shared__ float sW3[160], sL[160];
    const int lane = threadIdx.x, wy = threadIdx.y, tid = wy * 64 + lane;
    const int v0 = blockIdx.x * 64;
    const int cnt = (nv - v0 < 64) ? (nv - v0) : 64;

    if (tid < 160) sW3[tid] = W3[tid];
    load_stats(slab, Minv, sL, tid);
    __syncthreads();

    const short8* Lraw8 = (const short8*)Lraw;
    short8 vals[5];
#pragma unroll
    for (int u = 0; u < 5; ++u) {
        int it = tid + u * 256;
        int lr = it / 20, c = it - lr * 20;
        int v = v0 + ((lr < cnt) ? lr : cnt - 1);
        int row = (c < 10) ? v : v + nv;
        int cc = (c < 10) ? c : c - 10;
        vals[u] = Lraw8[(size_t)row * 10 + cc];
    }
#pragma unroll
    for (int u = 0; u < 5; ++u) {
        int it = tid + u * 256;
        int lr = it / 20, c = it - lr * 20;
        int v = v0 + ((lr < cnt) ? lr : cnt - 1);
        int cc = (c < 10) ? c : c - 10;
        int col = cc * 8;
        short8 o;
        uchar8 q;
#pragma unroll
        for (int j = 0; j < 8; ++j) {
            float f = (bf2f(vals[u][j]) - sL[col + j]) * sL[80 + col + j];
            o[j] = f2bf(f);
            q[j] = f2q8(f);
        }
        *(short8*)(lds + lr * SK + c * 8) = o;
        if (lr < cnt) {
            int lit = (c < 10) ? v : (v + nv);
            *(uchar8*)(Lb8 + (size_t)lit * 128 + cc * 8) = q;
        }
    }
    __syncthreads();   // staging crosses stripes

    const int quad = lane >> 4, l15 = lane & 15, wr0 = wy * 16, arow = wr0 + l15;

    f32x4 acc[10];
#pragma unroll
    for (int nb = 0; nb < 10; ++nb) { f32x4 z = {0.f, 0.f, 0.f, 0.f}; acc[nb] = z; }
    mfma_layer<5, 10>(lds, SK, W0p, acc, lane, arow);
    write_hidden<10>(lds, SK, acc, b0, l15, quad, wr0);

#pragma unroll
    for (int nb = 0; nb < 10; ++nb) { f32x4 z = {0.f, 0.f, 0.f, 0.f}; acc[nb] = z; }
    mfma_layer<5, 10>(lds, SK, W1p, acc, lane, arow);
    write_hidden<10>(lds, SK, acc, b1, l15, quad, wr0);

#pragma unroll
    for (int nb = 0; nb < 10; ++nb) { f32x4 z = {0.f, 0.f, 0.f, 0.f}; acc[nb] = z; }
    mfma_layer<5, 10>(lds, SK, W2p, acc, lane, arow);
    write_hidden<10>(lds, SK, acc, b2, l15, quad, wr0);
    __syncthreads();   // final dot reads across stripes

    int lrow = tid >> 2, t4 = tid & 3;
    float v = 0.f;
    for (int c = t4; c < 160; c += 4) v += bf2f(lds[lrow * SK + c]) * sW3[c];
    v += __shfl_down(v, 2, 4);
    v += __shfl_down(v, 1, 4);
    if (t4 == 0 && lrow < cnt) logits[v0 + lrow] = v + b3[0];
}

// ---------------- loss ----------------
__device__ __forceinline__ float softplusf(float x) {
    return fmaxf(x, 0.f) + log1pf(expf(-fabsf(x)));
}

__global__ void k_loss(const float* __restrict__ logits, const int* __restrict__ cellpk,
                       float* __restrict__ loss_acc, int cpg) {
    const int g = blockIdx.x;
    const int tid = threadIdx.x;
    float part = 0.f;
    int cend = (g + 1) * cpg;
    for (int c = g * cpg + tid; c < cend; c += 256) {
        float cs = 0.f;
#pragma unroll
        for (int t = 0; t < 3; ++t) {
            int cp = cellpk[c * 3 + t];
            float sign = (cp < 0) ? -1.f : 1.f;
            cs += softplusf(logits[cp & 0x7fffffff] * sign);
        }
        float vc = expf(-cs);
        part += vc * (-log1pf(LOSS_EPS - vc));
    }
    __shared__ float red[256];
    red[tid] = part;
    __syncthreads();
    for (int s = 128; s > 0; s >>= 1) {
        if (tid < s) red[tid] += red[tid + s];
        __syncthreads();
    }
    if (tid == 0) atomicAdd(loss_acc, sqrtf(red[0] + 1e-6f));
}

__global__ void k_output(float* __restrict__ dout, const float* __restrict__ logits,
                         const float* __restrict__ loss_acc, int nv) {
    int i = blockIdx.x * 256 + threadIdx.x;
    if (i < nv) dout[i] = logits[i];
    else if (i == nv) dout[i] = loss_acc[0] * (1.f / (float)NROUNDS);
}

// ---------------- host ----------------

extern "C" void kernel_launch(void* const* d_in, const int* in_sizes, int n_in,
                              void* d_out, int out_size, void* d_ws, size_t ws_size,
                              hipStream_t stream) {
    const int* lit_var    = (const int*)d_in[0];
    const int* lit_neg    = (const int*)d_in[1];
    const int* clause_idx = (const int*)d_in[2];
    const float* Lscale = (const float*)d_in[7];
    const float* Cscale = (const float*)d_in[8];
    const float* LCs    = (const float*)d_in[9];
    const float* CLs    = (const float*)d_in[10];
    const float* LuW0 = (const float*)d_in[11]; const float* Lub0 = (const float*)d_in[12];
    const float* LuW1 = (const float*)d_in[13]; const float* Lub1 = (const float*)d_in[14];
    const float* CuW0 = (const float*)d_in[15]; const float* Cub0 = (const float*)d_in[16];
    const float* CuW1 = (const float*)d_in[17]; const float* Cub1 = (const float*)d_in[18];
    const float* VsW0 = (const float*)d_in[19]; const float* Vsb0 = (const float*)d_in[20];
    const float* VsW1 = (const float*)d_in[21]; const float* Vsb1 = (const float*)d_in[22];
    const float* VsW2 = (const float*)d_in[23]; const float* Vsb2 = (const float*)d_in[24];
    const float* VsW3 = (const float*)d_in[25]; const float* Vsb3 = (const float*)d_in[26];

    const int ncell = in_sizes[0];          // 1,260,000
    const int ncl   = in_sizes[3];          // 420,000
    const int nv    = NV_CONST;
    const int nl    = 2 * nv;
    const int ng    = NG_CONST;

    size_t off = 0;
    auto A = [&](size_t bytes) -> void* {
        void* q = (char*)d_ws + off;
        off = (off + bytes + 255) & ~(size_t)255;
        return q;
    };
    short* Cb    = (short*)A((size_t)ncl * 80 * 2);    // raw C state (bf16, nt stream)
    short* Lraw  = (short*)A((size_t)nl * 80 * 2);     // raw L state (bf16)
    unsigned char* Lb8 = (unsigned char*)A((size_t)nl * 128);   // fp8 L, 128B/lit row
    unsigned char* Cb8 = (unsigned char*)A((size_t)ncl * 128);  // fp8 raw C, 128B/row
    float* logits = (float*)A((size_t)nv * 4);
    float* slabC  = (float*)A(33 * 160 * 4);
    float* slabL  = (float*)A(33 * 160 * 4);
    float* loss_a = (float*)A(256);
    int* litrow  = (int*)A((size_t)ncell * 4);
    int* lofs4   = (int*)A((size_t)ncl * 16);          // int4 per clause (permuted)
    int* cellpk  = (int*)A((size_t)ncell * 4);         // var | neg<<31
    int* row_ptr = (int*)A((size_t)(nl + 1) * 4);
    int* tmp     = (int*)A((size_t)nl * 4);
    int* cl_of   = (int*)A((size_t)ncell * 4);
    int* fhist   = (int*)A((size_t)nl * 4);            // first-lit histogram / cursor
    int* fbase   = (int*)A((size_t)(nl + 1) * 4);      // first-lit scan
    int* newpos  = (int*)A((size_t)ncl * 4);           // clause -> permuted pos
    short* CuW0p = (short*)A((size_t)10 * 5 * 64 * 16);
    short* CuW1p = (short*)A((size_t)5  * 5 * 64 * 16);
    short* LuW0p = (short*)A((size_t)15 * 8 * 64 * 16);
    short* LuW1p = (short*)A((size_t)5  * 8 * 64 * 16);
    short* VsW0p = (short*)A((size_t)10 * 5 * 64 * 16);
    short* VsW1p = (short*)A((size_t)10 * 5 * 64 * 16);
    short* VsW2p = (short*)A((size_t)10 * 5 * 64 * 16);

    const dim3 B64x4(64, 4, 1);

    // ---- setup ----
    k_zero_i<<<(nl + 255) / 256, 256, 0, stream>>>(tmp, nl);
    k_zero_i<<<(nl + 255) / 256, 256, 0, stream>>>(fhist, nl);
    k_init_slabs<<<(33 * 160 + 255) / 256, 256, 0, stream>>>(slabC, slabL, loss_a,
                                                             (float)ncl, (float)nl);
    k_litrow<<<(ncell + 255) / 256, 256, 0, stream>>>(lit_var, lit_neg, litrow, cellpk,
                                                      tmp, fhist, ncell, nv);
    k_scan4<<<1, 1024, 0, stream>>>(tmp, row_ptr, nl, ncell);
    k_scan4<<<1, 1024, 0, stream>>>(fhist, fbase, nl, ncl);
    k_copy_int<<<(nl + 255) / 256, 256, 0, stream>>>(tmp, row_ptr, nl);
    k_copy_int<<<(nl + 255) / 256, 256, 0, stream>>>(fhist, fbase, nl);
    k_place<<<(ncl + 255) / 256, 256, 0, stream>>>(litrow, fhist, newpos, lofs4, ncl);
    k_fill_csr<<<(ncell + 255) / 256, 256, 0, stream>>>(litrow, clause_idx, newpos,
                                                        tmp, cl_of, ncell);
    k_fill_b<<<(ncl * 80 + 255) / 256, 256, 0, stream>>>(Cb, ncl * 80, Cscale);
    k_fill_b<<<(nl * 80 + 255) / 256, 256, 0, stream>>>(Lraw, nl * 80, Lscale);
    k_fill_q8<<<(nl * 128 + 255) / 256, 256, 0, stream>>>(Lb8, nl * 128, Lscale);
    k_fill_q8<<<(ncl * 128 + 255) / 256, 256, 0, stream>>>(Cb8, ncl * 128, Cscale);
    k_pack_w<<<(10 * 5 * 64 + 255) / 256, 256, 0, stream>>>(CuW0, CuW0p, 160, 160, 5, 10);
    k_pack_w<<<(5  * 5 * 64 + 255) / 256, 256, 0, stream>>>(CuW1, CuW1p, 160, 80, 5, 5);
    k_pack_w<<<(15 * 8 * 64 + 255) / 256, 256, 0, stream>>>(LuW0, LuW0p, 240, 240, 8, 15);
    k_pack_w<<<(5  * 8 * 64 + 255) / 256, 256, 0, stream>>>(LuW1, LuW1p, 240, 80, 8, 5);
    k_pack_w<<<(10 * 5 * 64 + 255) / 256, 256, 0, stream>>>(VsW0, VsW0p, 160, 160, 5, 10);
    k_pack_w<<<(10 * 5 * 64 + 255) / 256, 256, 0, stream>>>(VsW1, VsW1p, 160, 160, 5, 10);
    k_pack_w<<<(10 * 5 * 64 + 255) / 256, 256, 0, stream>>>(VsW2, VsW2p, 160, 160, 5, 10);

    const int cblk  = (ncl + 63) / 64;          // 6563
    const int lblk  = nv / 32;                  // 3125
    const int vblk  = (nv + 63) / 64;           // 1563
    const float MinvC = 1.f / (float)ncl;
    const float MinvL = 1.f / (float)nl;

    for (int r = 0; r < NROUNDS; ++r) {
        float* sCr  = slabC + (size_t)r * 160;        // stats of input C state
        float* sCr1 = slabC + (size_t)(r + 1) * 160;  // stats of new C (this round)
        float* sLr  = slabL + (size_t)r * 160;        // stats of input L state
        float* sLr1 = slabL + (size_t)(r + 1) * 160;  // stats of new L (this round)
        k_c_update<<<cblk, B64x4, 0, stream>>>(
            Cb, Cb8, Lb8, (const int4*)lofs4, LCs, (const short8*)CuW0p, Cub0,
            (const short8*)CuW1p, Cub1, sCr, sCr1, MinvC, ncl);
        k_l_update<<<lblk, B64x4, 0, stream>>>(
            Lraw, Cb8, row_ptr, cl_of, CLs, sCr1, MinvC,
            (const short8*)LuW0p, Lub0, (const short8*)LuW1p, Lub1,
            sLr, sLr1, MinvL, nv);
        k_v_head<<<vblk, B64x4, 0, stream>>>(
            Lraw, sLr1, MinvL, (const short8*)VsW0p, Vsb0, (const short8*)VsW1p, Vsb1,
            (const short8*)VsW2p, Vsb2, VsW3, Vsb3, logits, Lb8, nv);
        k_loss<<<ng, 256, 0, stream>>>(logits, cellpk, loss_a, ncl / ng);
    }

    k_output<<<(nv + 1 + 255) / 256, 256, 0, stream>>>((float*)d_out, logits, loss_a, nv);
}

// Round 6
// 15437.808 us; speedup vs baseline: 1.0286x; 1.0286x over previous
//
#include <hip/hip_runtime.h>
#include <hip/hip_fp8.h>
#include <math.h>

// SimpleNeuroSAT on MI355X — round 20 (resubmit; prior run hit an infra
// "container failed twice" error, no kernel signal).
//  (1) Cb non-temporal load/store REMOVED: after round-19's CLb elimination
//      the hot set is Cb 67 + Cb8 54 + Lb8 26 + Lraw 32 + CSR 17 = 196MB,
//      which fits the 256MB L3. The nt policy (added when the set was 265MB)
//      was forcing a 134MB/round HBM round-trip (c_update FETCH=95MB of which
//      ~67MB is Cb). L3-resident Cb should cut c_update FETCH to ~30MB.
//  (2) Loss split to two stages: k_loss_part (8 sub-blocks/graph = 800 blocks,
//      per-graph atomic partials) + k_loss_fin (sqrt+sum+reset, 1 block).
//      Old single-stage used 100 blocks on 256 CUs (60% idle for ~45us).
// Keeps: CL-gather fused into l_update, clause first-lit sort, XCD swizzle,
// 128B fp8 rows, inline L norm, packed loss cells, converged staging.

#define NROUNDS 32
#define NORM_EPS 1e-3f
#define LOSS_EPS 1e-8f

static constexpr int NV_CONST = 100000;
static constexpr int NG_CONST = 100;
static constexpr int NSUB = 8;              // loss sub-blocks per graph

typedef __attribute__((ext_vector_type(8))) short short8;
typedef __attribute__((ext_vector_type(8))) unsigned char uchar8;
typedef __attribute__((ext_vector_type(16))) unsigned char uchar16;
typedef __attribute__((ext_vector_type(4))) float f32x4;

__device__ __forceinline__ short f2bf(float f) {
    union { float f; unsigned u; } x; x.f = f;
    unsigned r = x.u + 0x7fffu + ((x.u >> 16) & 1u);   // RNE
    return (short)(r >> 16);
}
__device__ __forceinline__ float bf2f(short s) {
    union { unsigned u; float f; } x; x.u = ((unsigned)(unsigned short)s) << 16;
    return x.f;
}
__device__ __forceinline__ unsigned char f2q8(float f) {
    f = fminf(fmaxf(f, -448.f), 448.f);    // e4m3fn finite range
    __hip_fp8_e4m3 t(f);
    return t.__x;
}
__device__ __forceinline__ float q82f(unsigned char b) {
    __hip_fp8_e4m3 t; t.__x = b;
    return (float)t;
}

// bijective XCD-aware block swizzle (m204): contiguous chunk per XCD
__device__ __forceinline__ int xcd_swz(int b, int nb) {
    int q = nb >> 3, r = nb & 7;
    int xcd = b & 7, idx = b >> 3;
    return (xcd < r ? xcd * (q + 1) : r * (q + 1) + (xcd - r) * q) + idx;
}

// ---------------- setup kernels ----------------

__global__ void k_zero_i(int* __restrict__ p, int n) {
    int i = blockIdx.x * 256 + threadIdx.x;
    if (i < n) p[i] = 0;
}
__global__ void k_zero_f(float* __restrict__ p, int n) {
    int i = blockIdx.x * 256 + threadIdx.x;
    if (i < n) p[i] = 0.f;
}
__global__ void k_fill_b(short* __restrict__ p, int n, const float* __restrict__ vp) {
    int i = blockIdx.x * 256 + threadIdx.x;
    if (i < n) p[i] = f2bf(*vp);
}
__global__ void k_fill_q8(unsigned char* __restrict__ p, int n, const float* __restrict__ vp) {
    int i = blockIdx.x * 256 + threadIdx.x;
    if (i < n) p[i] = f2q8(*vp);
}
__global__ void k_copy_int(int* __restrict__ dst, const int* __restrict__ src, int n) {
    int i = blockIdx.x * 256 + threadIdx.x;
    if (i < n) dst[i] = src[i];
}
// zero all slabs; slab[0] = identity for BOTH C and L (mean 0, rstd exactly 1)
__global__ void k_init_slabs(float* __restrict__ slabC, float* __restrict__ slabL,
                             float* __restrict__ loss_a, float nclf, float nlf) {
    int i = blockIdx.x * 256 + threadIdx.x;
    if (i < 33 * 160) {
        slabC[i] = (i >= 80 && i < 160) ? nclf * (1.f - NORM_EPS) : 0.f;
        slabL[i] = (i >= 80 && i < 160) ? nlf * (1.f - NORM_EPS) : 0.f;
    }
    if (i == 0) loss_a[0] = 0.f;
}

// litrow + packed loss cells + literal-CSR counts + first-lit histogram
__global__ void k_litrow(const int* __restrict__ lit_var, const int* __restrict__ lit_neg,
                         int* __restrict__ litrow, int* __restrict__ cellpk,
                         int* __restrict__ counts, int* __restrict__ fhist,
                         int ncell, int nv) {
    int i = blockIdx.x * 256 + threadIdx.x;
    if (i < ncell) {
        int vv = lit_var[i], ng = lit_neg[i];
        int r = vv + ng * nv;
        litrow[i] = r;
        cellpk[i] = vv | (ng << 31);
        atomicAdd(&counts[r], 1);
        if (i % 3 == 0) atomicAdd(&fhist[r], 1);   // clause key = first cell's row
    }
}

__launch_bounds__(1024)
__global__ void k_scan4(const int* __restrict__ counts, int* __restrict__ row_ptr,
                        int n, int total) {
    __shared__ int sd[1024];
    __shared__ int carry;
    int tid = threadIdx.x;
    if (tid == 0) carry = 0;
    __syncthreads();
    for (int base = 0; base < n; base += 4096) {
        int i0 = base + tid * 4;
        int a0 = (i0 + 0 < n) ? counts[i0 + 0] : 0;
        int a1 = (i0 + 1 < n) ? counts[i0 + 1] : 0;
        int a2 = (i0 + 2 < n) ? counts[i0 + 2] : 0;
        int a3 = (i0 + 3 < n) ? counts[i0 + 3] : 0;
        int s = a0 + a1 + a2 + a3;
        sd[tid] = s;
        __syncthreads();
        for (int off = 1; off < 1024; off <<= 1) {
            int t = (tid >= off) ? sd[tid - off] : 0;
            __syncthreads();
            sd[tid] += t;
            __syncthreads();
        }
        int excl = carry + sd[tid] - s;
        if (i0 + 0 < n) row_ptr[i0 + 0] = excl;
        if (i0 + 1 < n) row_ptr[i0 + 1] = excl + a0;
        if (i0 + 2 < n) row_ptr[i0 + 2] = excl + a0 + a1;
        if (i0 + 3 < n) row_ptr[i0 + 3] = excl + a0 + a1 + a2;
        __syncthreads();
        if (tid == 0) carry += sd[1023];
        __syncthreads();
    }
    if (tid == 0) row_ptr[n] = total;
}

// place clauses into first-lit-sorted order; write permuted lofs4 + newpos
__global__ void k_place(const int* __restrict__ litrow, int* __restrict__ fcur,
                        int* __restrict__ newpos, int* __restrict__ lofs4, int ncl) {
    int c = blockIdx.x * 256 + threadIdx.x;
    if (c < ncl) {
        int k = litrow[3 * c];
        int np = atomicAdd(&fcur[k], 1);
        newpos[c] = np;
        lofs4[np * 4 + 0] = litrow[3 * c + 0] * 8;
        lofs4[np * 4 + 1] = litrow[3 * c + 1] * 8;
        lofs4[np * 4 + 2] = litrow[3 * c + 2] * 8;
    }
}

__global__ void k_fill_csr(const int* __restrict__ litrow, const int* __restrict__ clause_idx,
                           const int* __restrict__ newpos,
                           int* __restrict__ cursor, int* __restrict__ cl_of, int ncell) {
    int i = blockIdx.x * 256 + threadIdx.x;
    if (i < ncell) {
        int r = litrow[i];
        int pos = atomicAdd(&cursor[r], 1);
        cl_of[pos] = newpos[clause_idx[i]];
    }
}

// Wp frag t=(nb*KB+kb)*64+lane holds W[kb*32+quad*8+j][nb*16+(lane&15)], zero-padded.
__global__ void k_pack_w(const float* __restrict__ W, short* __restrict__ Wp,
                         int K, int N, int KB, int NB) {
    int t = blockIdx.x * 256 + threadIdx.x;
    int tot = NB * KB * 64;
    if (t >= tot) return;
    int lane = t & 63;
    int kb = (t >> 6) % KB;
    int nb = t / (64 * KB);
    int quad = lane >> 4, l15 = lane & 15;
    int n = nb * 16 + l15;
#pragma unroll
    for (int j = 0; j < 8; ++j) {
        int k = kb * 32 + quad * 8 + j;
        float f = (k < K && n < N) ? W[(size_t)k * N + n] : 0.f;
        Wp[(size_t)t * 8 + j] = f2bf(f);
    }
}

// ---------------- MFMA building blocks ----------------

template <int KB, int NB>
__device__ __forceinline__ void mfma_layer(const short* lds, int SK,
                                           const short8* __restrict__ Wp,
                                           f32x4* acc, int lane, int arow) {
    const int quad8 = (lane >> 4) * 8;
    short8 a[KB];
#pragma unroll
    for (int kb = 0; kb < KB; ++kb)
        a[kb] = *(const short8*)(lds + arow * SK + kb * 32 + quad8);
#pragma unroll
    for (int kb = 0; kb < KB; ++kb)
#pragma unroll
        for (int nb = 0; nb < NB; ++nb)
            acc[nb] = __builtin_amdgcn_mfma_f32_16x16x32_bf16(
                a[kb], Wp[(nb * KB + kb) * 64 + lane], acc[nb], 0, 0, 0);
}

// wave-private: writes only rows wr0..wr0+15 (same stripe the wave reads)
template <int NB>
__device__ __forceinline__ void write_hidden(short* ldsH, int SKH, const f32x4* acc,
                                             const float* __restrict__ bias,
                                             int l15, int quad, int wr0) {
#pragma unroll
    for (int nb = 0; nb < NB; ++nb) {
        int c = nb * 16 + l15;
        float bv = bias[c];
#pragma unroll
        for (int reg = 0; reg < 4; ++reg) {
            int row = wr0 + quad * 4 + reg;
            float v = acc[nb][reg] + bv;
            v = fminf(fmaxf(v, 0.f), 6.f);
            ldsH[row * SKH + c] = f2bf(v);
        }
    }
}

// compute mean/rstd from an accum slab into shared sS[160] (callers sync after)
__device__ __forceinline__ void load_stats(const float* __restrict__ slab, float Minv,
                                           float* sS, int tid) {
    if (tid < 80) {
        float m = slab[tid] * Minv;
        float v = slab[80 + tid] * Minv - m * m;
        sS[tid] = m;
        sS[80 + tid] = rsqrtf(v + NORM_EPS);
    }
}

// ---------------- fused C update (16B fp8 LC gather, 128B-aligned rows) ----------------
__launch_bounds__(256, 2)
__global__ void k_c_update(short* __restrict__ Cb, unsigned char* __restrict__ Cb8,
                           const unsigned char* __restrict__ Lb8,
                           const int4* __restrict__ lofs4, const float* __restrict__ scp,
                           const short8* __restrict__ W0p, const float* __restrict__ b0,
                           const short8* __restrict__ W1p, const float* __restrict__ b1,
                           const float* __restrict__ prevSlab, float* __restrict__ nextSlab,
                           float Minv, int ncl) {
    constexpr int SK = 168;
    __shared__ short lds[64 * SK];
    __shared__ float sred[160], sC[160];
    const int lane = threadIdx.x, wy = threadIdx.y, tid = wy * 64 + lane;
    const int r0 = xcd_swz(blockIdx.x, gridDim.x) * 64;
    const int rows = (ncl - r0 < 64) ? (ncl - r0) : 64;

    if (tid < 160) sred[tid] = 0.f;
    load_stats(prevSlab, Minv, sC, tid);
    __syncthreads();

    const float s = *scp;
    const short8* Cbv = (const short8*)Cb;
    const uchar16* Lq = (const uchar16*)Lb8;

    // Converged direct staging: 64 rows x 10 bf16 chunks (640 items).
    // Cb is L3-resident now (196MB hot set < 256MB L3) — plain loads.
#pragma unroll
    for (int u = 0; u < 3; ++u) {
        int it = tid + u * 256;
        int itc = (it < 640) ? it : 639;
        int lr = itc / 10, c = itc - lr * 10;
        int cl = r0 + ((lr < rows) ? lr : rows - 1);
        short8 v = Cbv[(size_t)cl * 10 + c];
        int col = c * 8;
        short8 o;
#pragma unroll
        for (int j = 0; j < 8; ++j)
            o[j] = f2bf((bf2f(v[j]) - sC[col + j]) * sC[80 + col + j]);
        if (it < 640)
            *(short8*)(lds + lr * SK + col) = o;
    }
    // Converged gather staging: 64 rows x 5 fp8 16B chunks (320 items).
    // First-lit (o4.x) is sorted across the block -> near-sequential, L2-local.
#pragma unroll
    for (int u = 0; u < 2; ++u) {
        int it = tid + u * 256;
        int itc = (it < 320) ? it : 319;
        int lr = itc / 5, cc = itc - lr * 5;
        int cl = r0 + ((lr < rows) ? lr : rows - 1);
        int4 o4 = lofs4[cl];
        uchar16 va = Lq[(size_t)o4.x + cc];
        uchar16 vb = Lq[(size_t)o4.y + cc];
        uchar16 vc = Lq[(size_t)o4.z + cc];
        short8 o0, o1;
#pragma unroll
        for (int j = 0; j < 8; ++j) {
            o0[j] = f2bf((q82f(va[j]) + q82f(vb[j]) + q82f(vc[j])) * s);
            o1[j] = f2bf((q82f(va[8 + j]) + q82f(vb[8 + j]) + q82f(vc[8 + j])) * s);
        }
        if (it < 320) {
            *(short8*)(lds + lr * SK + 80 + cc * 16) = o0;
            *(short8*)(lds + lr * SK + 80 + cc * 16 + 8) = o1;
        }
    }
    __syncthreads();   // staging crosses stripes; everything after is wave-private

    const int quad = lane >> 4, l15 = lane & 15, wr0 = wy * 16, arow = wr0 + l15;

    f32x4 acc[10];
#pragma unroll
    for (int nb = 0; nb < 10; ++nb) { f32x4 z = {0.f, 0.f, 0.f, 0.f}; acc[nb] = z; }
    mfma_layer<5, 10>(lds, SK, W0p, acc, lane, arow);
    write_hidden<10>(lds, SK, acc, b0, l15, quad, wr0);

    f32x4 acc2[5];
#pragma unroll
    for (int nb = 0; nb < 5; ++nb) { f32x4 z = {0.f, 0.f, 0.f, 0.f}; acc2[nb] = z; }
    mfma_layer<5, 5>(lds, SK, W1p, acc2, lane, arow);

#pragma unroll
    for (int nb = 0; nb < 5; ++nb) {
        int cc = nb * 16 + l15;
        float bv = b1[cc];
        float s1 = 0.f, s2 = 0.f;
#pragma unroll
        for (int reg = 0; reg < 4; ++reg) {
            int lr = wr0 + quad * 4 + reg;
            if (lr < rows) {
                float v = acc2[nb][reg] + bv;
                Cb[(size_t)(r0 + lr) * 80 + cc] = f2bf(v);
                Cb8[(size_t)(r0 + lr) * 128 + cc] = f2q8(v);
                s1 += v; s2 += v * v;
            }
        }
        s1 += __shfl_xor(s1, 16); s1 += __shfl_xor(s1, 32);
        s2 += __shfl_xor(s2, 16); s2 += __shfl_xor(s2, 32);
        if (quad == 0) { atomicAdd(&sred[cc], s1); atomicAdd(&sred[80 + cc], s2); }
    }
    __syncthreads();
    if (tid < 160) atomicAdd(&nextSlab[tid], sred[tid]);
}

// ---------------- fused L update (CSR CL gather + MLP, inline L norm) ----------------
// paired rows [vb,vb+32) u [vb+nv,vb+nv+32); own+flip rows are block-local, so
// reading old Lraw and overwriting it in the epilogue is hazard-free.
// CL messages gathered here directly from fp8 Cb8 via literal CSR (no CLb).
__launch_bounds__(256, 2)
__global__ void k_l_update(short* __restrict__ Lraw,
                           const unsigned char* __restrict__ Cb8,
                           const int* __restrict__ row_ptr, const int* __restrict__ cl_of,
                           const float* __restrict__ clscp,
                           const float* __restrict__ cSlab, float MinvC,
                           const short8* __restrict__ W0p, const float* __restrict__ b0,
                           const short8* __restrict__ W1p, const float* __restrict__ b1,
                           const float* __restrict__ prevSlab, float* __restrict__ nextSlab,
                           float MinvL, int nv) {
    constexpr int SK = 264;
    __shared__ short lds[64 * SK];             // input K=256, then hidden 240+16pad
    __shared__ float sred[160], sL[160], sC[160];
    const int lane = threadIdx.x, wy = threadIdx.y, tid = wy * 64 + lane;
    const int vb = xcd_swz(blockIdx.x, gridDim.x) * 32;

    if (tid < 160) sred[tid] = 0.f;
    load_stats(prevSlab, MinvL, sL, tid);
    load_stats(cSlab, MinvC, sC, tid);
    __syncthreads();

    const short8* Lr8 = (const short8*)Lraw;
    // Phase 1: issue direct L loads (own + flip + zero tail), 64 rows x 22 chunks.
    short8 vals[6];
#pragma unroll
    for (int u = 0; u < 6; ++u) {
        int it = tid + u * 256;
        int itc = (it < 1408) ? it : 1407;
        int lr = itc / 22, c = itc - lr * 22;
        int own = (lr < 32) ? vb + lr : vb + nv + (lr - 32);
        int opp = (lr < 32) ? vb + nv + lr : vb + (lr - 32);
        int row = (c < 10) ? own : opp;               // c>=20 reads own c0 (discarded)
        int cc = (c < 10) ? c : ((c < 20) ? c - 10 : 0);
        vals[u] = Lr8[(size_t)row * 10 + cc];
    }

    // Phase 2: CSR CL gather, 64 rows x 5 fp8 16B chunks (320 items).
    // Row's clause list (via round-18 sort) has a contiguous first-lit run.
    const float cs = *clscp;
    const uchar16* Cq = (const uchar16*)Cb8;
#pragma unroll
    for (int u = 0; u < 2; ++u) {
        int it = tid + u * 256;
        if (it < 320) {
            int lr = it / 5, c16 = it - lr * 5;
            int r = (lr < 32) ? vb + lr : vb + nv + (lr - 32);
            int p0 = row_ptr[r], p1 = row_ptr[r + 1];
            float a[16];
#pragma unroll
            for (int j = 0; j < 16; ++j) a[j] = 0.f;
            int p = p0;
            for (; p + 4 <= p1; p += 4) {
                int i0 = cl_of[p], i1 = cl_of[p + 1], i2 = cl_of[p + 2], i3 = cl_of[p + 3];
                uchar16 v0 = Cq[(size_t)i0 * 8 + c16];
                uchar16 v1 = Cq[(size_t)i1 * 8 + c16];
                uchar16 v2 = Cq[(size_t)i2 * 8 + c16];
                uchar16 v3 = Cq[(size_t)i3 * 8 + c16];
#pragma unroll
                for (int j = 0; j < 16; ++j)
                    a[j] += (q82f(v0[j]) + q82f(v1[j])) + (q82f(v2[j]) + q82f(v3[j]));
            }
            for (; p < p1; ++p) {
                uchar16 v = Cq[(size_t)cl_of[p] * 8 + c16];
#pragma unroll
                for (int j = 0; j < 16; ++j) a[j] += q82f(v[j]);
            }
            float n = (float)(p1 - p0);
            int col = c16 * 16;
            short8 o0, o1;
#pragma unroll
            for (int j = 0; j < 8; ++j) {
                o0[j] = f2bf((a[j] - n * sC[col + j]) * sC[80 + col + j] * cs);
                o1[j] = f2bf((a[8 + j] - n * sC[col + 8 + j]) * sC[80 + col + 8 + j] * cs);
            }
            *(short8*)(lds + lr * SK + 80 + c16 * 16) = o0;
            *(short8*)(lds + lr * SK + 80 + c16 * 16 + 8) = o1;
        }
    }

    // Phase 3: normalize + store the direct L chunks.
#pragma unroll
    for (int u = 0; u < 6; ++u) {
        int it = tid + u * 256;
        int itc = (it < 1408) ? it : 1407;
        int lr = itc / 22, c = itc - lr * 22;
        short8 w = vals[u];
        if (c < 20) {
            int base = ((c < 10) ? c : c - 10) * 8;
#pragma unroll
            for (int j = 0; j < 8; ++j)
                w[j] = f2bf((bf2f(w[j]) - sL[base + j]) * sL[80 + base + j]);
        } else {
            short8 z = {0, 0, 0, 0, 0, 0, 0, 0};
            w = z;
        }
        int o = (c < 10) ? c * 8 : (c < 20) ? 160 + (c - 10) * 8 : 240 + (c - 20) * 8;
        if (it < 1408)
            *(short8*)(lds + lr * SK + o) = w;
    }
    __syncthreads();   // staging crosses stripes; rest is wave-private

    const int quad = lane >> 4, l15 = lane & 15, wr0 = wy * 16, arow = wr0 + l15;

    f32x4 acc[15];
#pragma unroll
    for (int nb = 0; nb < 15; ++nb) { f32x4 z = {0.f, 0.f, 0.f, 0.f}; acc[nb] = z; }
    mfma_layer<8, 15>(lds, SK, W0p, acc, lane, arow);
    write_hidden<15>(lds, SK, acc, b0, l15, quad, wr0);
    {   // zero-pad hidden cols 240..255 of OWN stripe (wave-private)
        int row = wr0 + (lane >> 2);
        int c = 240 + (lane & 3) * 4;
        short4 z; z.x = 0; z.y = 0; z.z = 0; z.w = 0;
        *(short4*)(lds + row * SK + c) = z;
    }

    f32x4 acc2[5];
#pragma unroll
    for (int nb = 0; nb < 5; ++nb) { f32x4 z = {0.f, 0.f, 0.f, 0.f}; acc2[nb] = z; }
    mfma_layer<8, 5>(lds, SK, W1p, acc2, lane, arow);

#pragma unroll
    for (int nb = 0; nb < 5; ++nb) {
        int cc = nb * 16 + l15;
        float bv = b1[cc];
        float s1 = 0.f, s2 = 0.f;
#pragma unroll
        for (int reg = 0; reg < 4; ++reg) {
            int lr = wr0 + quad * 4 + reg;
            int rabs = (lr < 32) ? vb + lr : vb + nv + (lr - 32);
            float v = acc2[nb][reg] + bv;
            Lraw[(size_t)rabs * 80 + cc] = f2bf(v);
            s1 += v; s2 += v * v;
        }
        s1 += __shfl_xor(s1, 16); s1 += __shfl_xor(s1, 32);
        s2 += __shfl_xor(s2, 16); s2 += __shfl_xor(s2, 32);
        if (quad == 0) { atomicAdd(&sred[cc], s1); atomicAdd(&sred[80 + cc], s2); }
    }
    __syncthreads();
    if (tid < 160) atomicAdd(&nextSlab[tid], sred[tid]);
}

// ---------------- fused V head (4 layers; emits Lb8 fp8 for next round) ----------------
__launch_bounds__(256, 2)
__global__ void k_v_head(const short* __restrict__ Lraw, const float* __restrict__ slab,
                         float Minv,
                         const short8* __restrict__ W0p, const float* __restrict__ b0,
                         const short8* __restrict__ W1p, const float* __restrict__ b1,
                         const short8* __restrict__ W2p, const float* __restrict__ b2,
                         const float* __restrict__ W3, const float* __restrict__ b3,
                         float* __restrict__ logits,
                         unsigned char* __restrict__ Lb8, int nv) {
    constexpr int SK = 168;
    __shared__ short lds[64 * SK];
    __shared__ float sW3[160], sL[160];
    const int lane = threadIdx.x, wy = threadIdx.y, tid = wy * 64 + lane;
    const int v0 = blockIdx.x * 64;
    const int cnt = (nv - v0 < 64) ? (nv - v0) : 64;

    if (tid < 160) sW3[tid] = W3[tid];
    load_stats(slab, Minv, sL, tid);
    __syncthreads();

    const short8* Lraw8 = (const short8*)Lraw;
    short8 vals[5];
#pragma unroll
    for (int u = 0; u < 5; ++u) {
        int it = tid + u * 256;
        int lr = it / 20, c = it - lr * 20;
        int v = v0 + ((lr < cnt) ? lr : cnt - 1);
        int row = (c < 10) ? v : v + nv;
        int cc = (c < 10) ? c : c - 10;
        vals[u] = Lraw8[(size_t)row * 10 + cc];
    }
#pragma unroll
    for (int u = 0; u < 5; ++u) {
        int it = tid + u * 256;
        int lr = it / 20, c = it - lr * 20;
        int v = v0 + ((lr < cnt) ? lr : cnt - 1);
        int cc = (c < 10) ? c : c - 10;
        int col = cc * 8;
        short8 o;
        uchar8 q;
#pragma unroll
        for (int j = 0; j < 8; ++j) {
            float f = (bf2f(vals[u][j]) - sL[col + j]) * sL[80 + col + j];
            o[j] = f2bf(f);
            q[j] = f2q8(f);
        }
        *(short8*)(lds + lr * SK + c * 8) = o;
        if (lr < cnt) {
            int lit = (c < 10) ? v : (v + nv);
            *(uchar8*)(Lb8 + (size_t)lit * 128 + cc * 8) = q;
        }
    }
    __syncthreads();   // staging crosses stripes

    const int quad = lane >> 4, l15 = lane & 15, wr0 = wy * 16, arow = wr0 + l15;

    f32x4 acc[10];
#pragma unroll
    for (int nb = 0; nb < 10; ++nb) { f32x4 z = {0.f, 0.f, 0.f, 0.f}; acc[nb] = z; }
    mfma_layer<5, 10>(lds, SK, W0p, acc, lane, arow);
    write_hidden<10>(lds, SK, acc, b0, l15, quad, wr0);

#pragma unroll
    for (int nb = 0; nb < 10; ++nb) { f32x4 z = {0.f, 0.f, 0.f, 0.f}; acc[nb] = z; }
    mfma_layer<5, 10>(lds, SK, W1p, acc, lane, arow);
    write_hidden<10>(lds, SK, acc, b1, l15, quad, wr0);

#pragma unroll
    for (int nb = 0; nb < 10; ++nb) { f32x4 z = {0.f, 0.f, 0.f, 0.f}; acc[nb] = z; }
    mfma_layer<5, 10>(lds, SK, W2p, acc, lane, arow);
    write_hidden<10>(lds, SK, acc, b2, l15, quad, wr0);
    __syncthreads();   // final dot reads across stripes

    int lrow = tid >> 2, t4 = tid & 3;
    float v = 0.f;
    for (int c = t4; c < 160; c += 4) v += bf2f(lds[lrow * SK + c]) * sW3[c];
    v += __shfl_down(v, 2, 4);
    v += __shfl_down(v, 1, 4);
    if (t4 == 0 && lrow < cnt) logits[v0 + lrow] = v + b3[0];
}

// ---------------- loss (two-stage, 8 sub-blocks per graph) ----------------
__device__ __forceinline__ float softplusf(float x) {
    return fmaxf(x, 0.f) + log1pf(expf(-fabsf(x)));
}

__global__ void k_loss_part(const float* __restrict__ logits, const int* __restrict__ cellpk,
                            float* __restrict__ pgsum, int cpg) {
    const int g = blockIdx.x / NSUB, sb = blockIdx.x % NSUB;
    const int tid = threadIdx.x;
    const int span = cpg / NSUB;                  // 4200/8 = 525
    const int c0 = g * cpg + sb * span;
    const int c1 = (sb == NSUB - 1) ? (g + 1) * cpg : c0 + span;
    float part = 0.f;
    for (int c = c0 + tid; c < c1; c += 256) {
        float cs = 0.f;
#pragma unroll
        for (int t = 0; t < 3; ++t) {
            int cp = cellpk[c * 3 + t];
            float sign = (cp < 0) ? -1.f : 1.f;
            cs += softplusf(logits[cp & 0x7fffffff] * sign);
        }
        float vc = expf(-cs);
        part += vc * (-log1pf(LOSS_EPS - vc));
    }
    __shared__ float red[256];
    red[tid] = part;
    __syncthreads();
    for (int s = 128; s > 0; s >>= 1) {
        if (tid < s) red[tid] += red[tid + s];
        __syncthreads();
    }
    if (tid == 0) atomicAdd(&pgsum[g], red[0]);
}

__global__ void k_loss_fin(float* __restrict__ pgsum, float* __restrict__ loss_acc, int ng) {
    const int tid = threadIdx.x;    // 1 block, 128 threads
    float v = 0.f;
    if (tid < ng) {
        v = sqrtf(pgsum[tid] + 1e-6f);
        pgsum[tid] = 0.f;           // reset for next round
    }
    __shared__ float red[128];
    red[tid] = v;
    __syncthreads();
    for (int s = 64; s > 0; s >>= 1) {
        if (tid < s) red[tid] += red[tid + s];
        __syncthreads();
    }
    if (tid == 0) atomicAdd(loss_acc, red[0]);
}

__global__ void k_output(float* __restrict__ dout, const float* __restrict__ logits,
                         const float* __restrict__ loss_acc, int nv) {
    int i = blockIdx.x * 256 + threadIdx.x;
    if (i < nv) dout[i] = logits[i];
    else if (i == nv) dout[i] = loss_acc[0] * (1.f / (float)NROUNDS);
}

// ---------------- host ----------------

extern "C" void kernel_launch(void* const* d_in, const int* in_sizes, int n_in,
                              void* d_out, int out_size, void* d_ws, size_t ws_size,
                              hipStream_t stream) {
    const int* lit_var    = (const int*)d_in[0];
    const int* lit_neg    = (const int*)d_in[1];
    const int* clause_idx = (const int*)d_in[2];
    const float* Lscale = (const float*)d_in[7];
    const float* Cscale = (const float*)d_in[8];
    const float* LCs    = (const float*)d_in[9];
    const float* CLs    = (const float*)d_in[10];
    const float* LuW0 = (const float*)d_in[11]; const float* Lub0 = (const float*)d_in[12];
    const float* LuW1 = (const float*)d_in[13]; const float* Lub1 = (const float*)d_in[14];
    const float* CuW0 = (const float*)d_in[15]; const float* Cub0 = (const float*)d_in[16];
    const float* CuW1 = (const float*)d_in[17]; const float* Cub1 = (const float*)d_in[18];
    const float* VsW0 = (const float*)d_in[19]; const float* Vsb0 = (const float*)d_in[20];
    const float* VsW1 = (const float*)d_in[21]; const float* Vsb1 = (const float*)d_in[22];
    const float* VsW2 = (const float*)d_in[23]; const float* Vsb2 = (const float*)d_in[24];
    const float* VsW3 = (const float*)d_in[25]; const float* Vsb3 = (const float*)d_in[26];

    const int ncell = in_sizes[0];          // 1,260,000
    const int ncl   = in_sizes[3];          // 420,000
    const int nv    = NV_CONST;
    const int nl    = 2 * nv;
    const int ng    = NG_CONST;

    size_t off = 0;
    auto A = [&](size_t bytes) -> void* {
        void* q = (char*)d_ws + off;
        off = (off + bytes + 255) & ~(size_t)255;
        return q;
    };
    short* Cb    = (short*)A((size_t)ncl * 80 * 2);    // raw C state (bf16, L3-resident)
    short* Lraw  = (short*)A((size_t)nl * 80 * 2);     // raw L state (bf16)
    unsigned char* Lb8 = (unsigned char*)A((size_t)nl * 128);   // fp8 L, 128B/lit row
    unsigned char* Cb8 = (unsigned char*)A((size_t)ncl * 128);  // fp8 raw C, 128B/row
    float* logits = (float*)A((size_t)nv * 4);
    float* slabC  = (float*)A(33 * 160 * 4);
    float* slabL  = (float*)A(33 * 160 * 4);
    float* loss_a = (float*)A(256);
    float* pgsum  = (float*)A((size_t)ng * 4);
    int* litrow  = (int*)A((size_t)ncell * 4);
    int* lofs4   = (int*)A((size_t)ncl * 16);          // int4 per clause (permuted)
    int* cellpk  = (int*)A((size_t)ncell * 4);         // var | neg<<31
    int* row_ptr = (int*)A((size_t)(nl + 1) * 4);
    int* tmp     = (int*)A((size_t)nl * 4);
    int* cl_of   = (int*)A((size_t)ncell * 4);
    int* fhist   = (int*)A((size_t)nl * 4);            // first-lit histogram / cursor
    int* fbase   = (int*)A((size_t)(nl + 1) * 4);      // first-lit scan
    int* newpos  = (int*)A((size_t)ncl * 4);           // clause -> permuted pos
    short* CuW0p = (short*)A((size_t)10 * 5 * 64 * 16);
    short* CuW1p = (short*)A((size_t)5  * 5 * 64 * 16);
    short* LuW0p = (short*)A((size_t)15 * 8 * 64 * 16);
    short* LuW1p = (short*)A((size_t)5  * 8 * 64 * 16);
    short* VsW0p = (short*)A((size_t)10 * 5 * 64 * 16);
    short* VsW1p = (short*)A((size_t)10 * 5 * 64 * 16);
    short* VsW2p = (short*)A((size_t)10 * 5 * 64 * 16);

    const dim3 B64x4(64, 4, 1);

    // ---- setup ----
    k_zero_i<<<(nl + 255) / 256, 256, 0, stream>>>(tmp, nl);
    k_zero_i<<<(nl + 255) / 256, 256, 0, stream>>>(fhist, nl);
    k_zero_f<<<1, 256, 0, stream>>>(pgsum, ng);
    k_init_slabs<<<(33 * 160 + 255) / 256, 256, 0, stream>>>(slabC, slabL, loss_a,
                                                             (float)ncl, (float)nl);
    k_litrow<<<(ncell + 255) / 256, 256, 0, stream>>>(lit_var, lit_neg, litrow, cellpk,
                                                      tmp, fhist, ncell, nv);
    k_scan4<<<1, 1024, 0, stream>>>(tmp, row_ptr, nl, ncell);
    k_scan4<<<1, 1024, 0, stream>>>(fhist, fbase, nl, ncl);
    k_copy_int<<<(nl + 255) / 256, 256, 0, stream>>>(tmp, row_ptr, nl);
    k_copy_int<<<(nl + 255) / 256, 256, 0, stream>>>(fhist, fbase, nl);
    k_place<<<(ncl + 255) / 256, 256, 0, stream>>>(litrow, fhist, newpos, lofs4, ncl);
    k_fill_csr<<<(ncell + 255) / 256, 256, 0, stream>>>(litrow, clause_idx, newpos,
                                                        tmp, cl_of, ncell);
    k_fill_b<<<(ncl * 80 + 255) / 256, 256, 0, stream>>>(Cb, ncl * 80, Cscale);
    k_fill_b<<<(nl * 80 + 255) / 256, 256, 0, stream>>>(Lraw, nl * 80, Lscale);
    k_fill_q8<<<(nl * 128 + 255) / 256, 256, 0, stream>>>(Lb8, nl * 128, Lscale);
    k_fill_q8<<<(ncl * 128 + 255) / 256, 256, 0, stream>>>(Cb8, ncl * 128, Cscale);
    k_pack_w<<<(10 * 5 * 64 + 255) / 256, 256, 0, stream>>>(CuW0, CuW0p, 160, 160, 5, 10);
    k_pack_w<<<(5  * 5 * 64 + 255) / 256, 256, 0, stream>>>(CuW1, CuW1p, 160, 80, 5, 5);
    k_pack_w<<<(15 * 8 * 64 + 255) / 256, 256, 0, stream>>>(LuW0, LuW0p, 240, 240, 8, 15);
    k_pack_w<<<(5  * 8 * 64 + 255) / 256, 256, 0, stream>>>(LuW1, LuW1p, 240, 80, 8, 5);
    k_pack_w<<<(10 * 5 * 64 + 255) / 256, 256, 0, stream>>>(VsW0, VsW0p, 160, 160, 5, 10);
    k_pack_w<<<(10 * 5 * 64 + 255) / 256, 256, 0, stream>>>(VsW1, VsW1p, 160, 160, 5, 10);
    k_pack_w<<<(10 * 5 * 64 + 255) / 256, 256, 0, stream>>>(VsW2, VsW2p, 160, 160, 5, 10);

    const int cblk  = (ncl + 63) / 64;          // 6563
    const int lblk  = nv / 32;                  // 3125
    const int vblk  = (nv + 63) / 64;           // 1563
    const float MinvC = 1.f / (float)ncl;
    const float MinvL = 1.f / (float)nl;

    for (int r = 0; r < NROUNDS; ++r) {
        float* sCr  = slabC + (size_t)r * 160;        // stats of input C state
        float* sCr1 = slabC + (size_t)(r + 1) * 160;  // stats of new C (this round)
        float* sLr  = slabL + (size_t)r * 160;        // stats of input L state
        float* sLr1 = slabL + (size_t)(r + 1) * 160;  // stats of new L (this round)
        k_c_update<<<cblk, B64x4, 0, stream>>>(
            Cb, Cb8, Lb8, (const int4*)lofs4, LCs, (const short8*)CuW0p, Cub0,
            (const short8*)CuW1p, Cub1, sCr, sCr1, MinvC, ncl);
        k_l_update<<<lblk, B64x4, 0, stream>>>(
            Lraw, Cb8, row_ptr, cl_of, CLs, sCr1, MinvC,
            (const short8*)LuW0p, Lub0, (const short8*)LuW1p, Lub1,
            sLr, sLr1, MinvL, nv);
        k_v_head<<<vblk, B64x4, 0, stream>>>(
            Lraw, sLr1, MinvL, (const short8*)VsW0p, Vsb0, (const short8*)VsW1p, Vsb1,
            (const short8*)VsW2p, Vsb2, VsW3, Vsb3, logits, Lb8, nv);
        k_loss_part<<<ng * NSUB, 256, 0, stream>>>(logits, cellpk, pgsum, ncl / ng);
        k_loss_fin<<<1, 128, 0, stream>>>(pgsum, loss_a, ng);
    }

    k_output<<<(nv + 1 + 255) / 256, 256, 0, stream>>>((float*)d_out, logits, loss_a, nv);
}